// Round 9
// baseline (309.503 us; speedup 1.0000x reference)
//
#include <hip/hip_runtime.h>
#include <hip/hip_bf16.h>

#define D_MODEL 1024
#define T_SEQ   2048
#define BATCH   4
#define NHEADS  16
#define HDIM    64
#define M_ROWS  (BATCH * T_SEQ)   // 8192
#define QSCALE  (0.125f * 1.44269504088896340736f)   // 1/sqrt(64) * log2(e)

typedef unsigned short ushortT;
typedef __attribute__((ext_vector_type(4))) float f32x4;
typedef __attribute__((ext_vector_type(8))) short s16x8;

#define GP(p) ((const __attribute__((address_space(1))) void*)(p))
#define LP(p) ((__attribute__((address_space(3))) void*)(p))

static __device__ __forceinline__ ushortT f2b(float f) {
    union { float f; unsigned u; } v; v.f = f;
    unsigned r = v.u + 0x7fffu + ((v.u >> 16) & 1u);
    return (ushortT)(r >> 16);
}

// packed f32x2 -> bf16x2 (hardware cvt, S0->low, S1->high)
static __device__ __forceinline__ unsigned cvtpk(float lo, float hi) {
    unsigned r;
    asm("v_cvt_pk_bf16_f32 %0, %1, %2" : "=v"(r) : "v"(lo), "v"(hi));
    return r;
}

// ---- fused cast: x + 4 weights, fp32 -> bf16, XOR-swizzled by (row&7) ----
__global__ void cast_all(const float* __restrict__ x,
                         const float* __restrict__ Wq, const float* __restrict__ Wk,
                         const float* __restrict__ Wv, const float* __restrict__ Wo,
                         ushortT* __restrict__ dst) {
    const int i = blockIdx.x * 256 + threadIdx.x;
    const float* src; int g, ob;
    if (i < 1048576)      { src = x;  g = i;           ob = 0; }
    else if (i < 1179648) { src = Wq; g = i - 1048576; ob = 1048576; }
    else if (i < 1310720) { src = Wk; g = i - 1179648; ob = 1179648; }
    else if (i < 1441792) { src = Wv; g = i - 1310720; ob = 1310720; }
    else                  { src = Wo; g = i - 1441792; ob = 1441792; }
    const float4* s = (const float4*)src;
    float4 a = s[g * 2], b = s[g * 2 + 1];
    s16x8 r;
    r[0] = f2b(a.x); r[1] = f2b(a.y); r[2] = f2b(a.z); r[3] = f2b(a.w);
    r[4] = f2b(b.x); r[5] = f2b(b.y); r[6] = f2b(b.z); r[7] = f2b(b.w);
    ((s16x8*)dst)[ob + (g ^ ((g >> 7) & 7))] = r;
}

// ================= shared GEMM machinery (single-buffer, 2-barrier, m97-style) ======
// A and Bw stored granule-swizzled: elem[m][k ^ ((m&7)<<3)].
// 128x128 tile, BK=64, 4 waves (2x2), 16 K-steps. LDS 32KB -> 5 blocks/CU.

#define GEMM_PREAMBLE()                                                  \
    const int tid  = threadIdx.x;                                        \
    const int wave = tid >> 6, lane = tid & 63;                          \
    const int wm = wave >> 1, wn = wave & 1;                             \
    const int lr = lane & 15, lh = lane >> 4;                            \
    const int srow = tid >> 3;                                           \
    const int sg   = tid & 7;                                            \
    f32x4 acc[4][4] = {};                                                \
    const ushortT* Ag = A  + (size_t)(m0 + srow) * 1024 + sg * 8;        \
    const ushortT* Bg = Bw + (size_t)(n0 + srow) * 1024 + sg * 8;

#define STAGE_G(k0)                                                                    \
    do {                                                                               \
        _Pragma("unroll")                                                              \
        for (int is = 0; is < 4; ++is) {                                               \
            __builtin_amdgcn_global_load_lds(GP(Ag + (size_t)(is * 32) * 1024 + (k0)), \
                                             LP(&As[is * 2048 + tid * 8]), 16, 0, 0);  \
            __builtin_amdgcn_global_load_lds(GP(Bg + (size_t)(is * 32) * 1024 + (k0)), \
                                             LP(&Bs[is * 2048 + tid * 8]), 16, 0, 0);  \
        }                                                                              \
    } while (0)

#define COMPUTE_G()                                                                    \
    do {                                                                               \
        _Pragma("unroll")                                                              \
        for (int kk = 0; kk < 2; ++kk) {                                               \
            s16x8 af[4], bfr[4];                                                       \
            const int g = ((kk * 4 + lh) ^ (lr & 7)) * 8;                              \
            _Pragma("unroll")                                                          \
            for (int i = 0; i < 4; ++i)                                                \
                af[i] = *(const s16x8*)&As[(wm * 64 + i * 16 + lr) * 64 + g];          \
            _Pragma("unroll")                                                          \
            for (int j = 0; j < 4; ++j)                                                \
                bfr[j] = *(const s16x8*)&Bs[(wn * 64 + j * 16 + lr) * 64 + g];         \
            __builtin_amdgcn_s_setprio(1);                                             \
            _Pragma("unroll")                                                          \
            for (int i = 0; i < 4; ++i)                                                \
                _Pragma("unroll")                                                      \
                for (int j = 0; j < 4; ++j)                                            \
                    acc[i][j] = __builtin_amdgcn_mfma_f32_16x16x32_bf16(af[i], bfr[j], acc[i][j], 0, 0, 0); \
            __builtin_amdgcn_s_setprio(0);                                             \
        }                                                                              \
    } while (0)

#define GEMM_KLOOP()                        \
    for (int t = 0; t < 16; ++t) {          \
        STAGE_G(t * 64);                    \
        __syncthreads();                    \
        COMPUTE_G();                        \
        __syncthreads();                    \
    }

// ---- fused QKV GEMM: grid (64, 24); seg = y>>3 (0=Q,1=K,2=V) ----
__global__ __launch_bounds__(256, 5) void qkv_gemm(
    const ushortT* __restrict__ A,
    const ushortT* __restrict__ Wq, const ushortT* __restrict__ Wk, const ushortT* __restrict__ Wv,
    const float* __restrict__ bq, const float* __restrict__ bk, const float* __restrict__ bv,
    ushortT* __restrict__ Qb, ushortT* __restrict__ Kb, ushortT* __restrict__ Vtb)
{
    __shared__ __attribute__((aligned(16))) ushortT As[128 * 64];
    __shared__ __attribute__((aligned(16))) ushortT Bs[128 * 64];

    const int seg = blockIdx.y >> 3;
    const int m0 = blockIdx.x * 128, n0 = (blockIdx.y & 7) * 128;
    const ushortT* Bw   = (seg == 0) ? Wq : (seg == 1) ? Wk : Wv;
    const float*   bias = (seg == 0) ? bq : (seg == 1) ? bk : bv;
    const float    scale = (seg == 0) ? QSCALE : 1.0f;

    GEMM_PREAMBLE();
    GEMM_KLOOP();

    ushortT* outp = (seg == 0) ? Qb : (seg == 1) ? Kb : Vtb;
    #pragma unroll
    for (int i = 0; i < 4; ++i) {
        #pragma unroll
        for (int j = 0; j < 4; ++j) {
            const int c = n0 + wn * 64 + j * 16 + lr;
            const float bv_ = bias[c];
            #pragma unroll
            for (int e = 0; e < 4; ++e) {
                const int r = m0 + wm * 64 + i * 16 + lh * 4 + e;
                const float val = (acc[i][j][e] + bv_) * scale;
                const int b = r >> 11, t = r & 2047;
                const int h = c >> 6,  d = c & 63;
                size_t idx;
                if (seg == 2)      idx = ((size_t)(b * NHEADS + h) * HDIM + d) * T_SEQ + (t ^ ((d & 7) << 3));
                else if (seg == 1) idx = ((size_t)(b * NHEADS + h) * T_SEQ + t) * HDIM + (d ^ ((t & 7) << 3));
                else               idx = ((size_t)(b * NHEADS + h) * T_SEQ + t) * HDIM + d;
                outp[idx] = f2b(val);
            }
        }
    }
}

// ---- output GEMM: grid (64, 8), fp32 out ----
__global__ __launch_bounds__(256, 5) void out_gemm(
    const ushortT* __restrict__ A, const ushortT* __restrict__ Bw,
    const float* __restrict__ bias, float* __restrict__ outp)
{
    __shared__ __attribute__((aligned(16))) ushortT As[128 * 64];
    __shared__ __attribute__((aligned(16))) ushortT Bs[128 * 64];

    const int m0 = blockIdx.x * 128, n0 = blockIdx.y * 128;

    GEMM_PREAMBLE();
    GEMM_KLOOP();

    #pragma unroll
    for (int i = 0; i < 4; ++i) {
        #pragma unroll
        for (int j = 0; j < 4; ++j) {
            const int c = n0 + wn * 64 + j * 16 + lr;
            const float bv_ = bias[c];
            #pragma unroll
            for (int e = 0; e < 4; ++e) {
                const int r = m0 + wm * 64 + i * 16 + lh * 4 + e;
                outp[(size_t)r * 1024 + c] = acc[i][j][e] + bv_;
            }
        }
    }
}

// ---------------- flash attention, causal, swapped-operand softmax ----------------
// 8-wave blocks (512 thr), 128 q-rows/block sharing one K/V stream.
// Grid 1024 = 64 bh x 16 q-groups; LPT order (big qg first) + XCD head-grouping.
// LDS 48KB -> 3 blocks/CU = 24 waves/CU.
// Q pre-scaled by QSCALE (log2 domain). K: (BH,T,64) swizzled d^=(t&7)<<3.
// Vt: (BH,64,T) swizzled t^=(d&7)<<3.  Ob out: (B,T,D) bf16 swizzled c^=(t&7)<<3.
__global__ __launch_bounds__(512, 6) void attn_fwd(
    const ushortT* __restrict__ Qb, const ushortT* __restrict__ Kb,
    const ushortT* __restrict__ Vt, ushortT* __restrict__ Ob)
{
    __shared__ __attribute__((aligned(16))) ushortT Ks[2][64 * 64];
    __shared__ __attribute__((aligned(16))) ushortT Vs[2][64 * 64];
    __shared__ __attribute__((aligned(16))) ushortT Ps[8][16 * 64];

    const int tid = threadIdx.x;
    const int w = tid >> 6, lane = tid & 63;
    const int lr = lane & 15, lh = lane >> 4;

    const int blk  = blockIdx.x;
    const int bh   = (blk & 7) * 8 + ((blk >> 3) & 7);  // 8 heads per XCD
    const int grp  = blk >> 6;                          // 0..15
    const int qg64 = (15 - grp) * 2;                    // q-group start in 64-tiles (LPT)
    const int q0   = qg64 * 64;                         // q-group start row (multiple of 128)
    const int last = qg64 + 1;                          // last KV tile index

    const int srow = tid >> 3;       // 0..63
    const int sk   = (tid & 7) * 8;

    const ushortT* Kbh = Kb + (size_t)bh * T_SEQ * HDIM;
    const ushortT* Vbh = Vt + (size_t)bh * HDIM * T_SEQ;
    const int b = bh >> 4, h = bh & 15;

    const int g0 = (lh       ^ (lr & 7)) * 8;
    const int g1 = ((4 + lh) ^ (lr & 7)) * 8;

    // single-issue staging: 512 thr x 16B = 8KB = one 64x64 bf16 tile
    #define STAGE(buf, kt_) do { \
        const int k0_ = (kt_) * 64; \
        __builtin_amdgcn_global_load_lds(GP(Kbh + (size_t)(k0_ + srow) * HDIM + sk), \
                                         LP(&Ks[buf][srow * 64 + sk]), 16, 0, 0); \
        __builtin_amdgcn_global_load_lds(GP(Vbh + (size_t)srow * T_SEQ + k0_ + sk), \
                                         LP(&Vs[buf][srow * 64 + sk]), 16, 0, 0); \
    } while (0)

    STAGE(0, 0);

    // Q fragments: B-operand (col=q=lane&15) for swapped QK^T
    const ushortT* qrow = Qb + ((size_t)bh * T_SEQ + q0 + w * 16 + lr) * HDIM;
    const s16x8 qf0 = *(const s16x8*)(qrow + lh * 8);
    const s16x8 qf1 = *(const s16x8*)(qrow + 32 + lh * 8);

    float m_r = -1e30f, l_r = 0.f;
    f32x4 o[4] = {};   // O^T: col=q=lr, row=d=ni*16+lh*4+e

    const int dt = qg64 + (w >> 2);   // this wave's diagonal KV tile

    __syncthreads();

    for (int kt = 0; kt <= last; ++kt) {
        const int cur = kt & 1;
        if (kt < last) STAGE(cur ^ 1, kt + 1);

        if (kt <= dt) {   // skip fully-masked tiles (waves 0-3 at kt=last)
            // S^T = K Q^T: A=K-frag, B=Q-frag.  s[ni][e] = S[q][kv=ni*16+lh*4+e]
            f32x4 s[4];
            __builtin_amdgcn_s_setprio(1);
            #pragma unroll
            for (int ni = 0; ni < 4; ++ni) {
                const int rr = ni * 16 + lr;
                s16x8 b0 = *(const s16x8*)&Ks[cur][rr * 64 + g0];
                s16x8 b1 = *(const s16x8*)&Ks[cur][rr * 64 + g1];
                f32x4 t = {};
                t = __builtin_amdgcn_mfma_f32_16x16x32_bf16(b0, qf0, t, 0, 0, 0);
                t = __builtin_amdgcn_mfma_f32_16x16x32_bf16(b1, qf1, t, 0, 0, 0);
                s[ni] = t;
            }
            __builtin_amdgcn_s_setprio(0);

            if (kt == dt) {   // diagonal tile: mask kv > q (local offset (w&3)*16+lr)
                #pragma unroll
                for (int ni = 0; ni < 4; ++ni)
                    #pragma unroll
                    for (int e = 0; e < 4; ++e)
                        if (ni * 16 + lh * 4 + e > (w & 3) * 16 + lr) s[ni][e] = -1e30f;
            }

            // per-lane row max (pairwise tree) + 2 shfl to combine lh groups
            float pm;
            {
                float a0 = fmaxf(fmaxf(s[0][0], s[0][1]), fmaxf(s[0][2], s[0][3]));
                float a1 = fmaxf(fmaxf(s[1][0], s[1][1]), fmaxf(s[1][2], s[1][3]));
                float a2 = fmaxf(fmaxf(s[2][0], s[2][1]), fmaxf(s[2][2], s[2][3]));
                float a3 = fmaxf(fmaxf(s[3][0], s[3][1]), fmaxf(s[3][2], s[3][3]));
                pm = fmaxf(fmaxf(a0, a1), fmaxf(a2, a3));
            }
            pm = fmaxf(pm, __shfl_xor(pm, 16, 64));
            pm = fmaxf(pm, __shfl_xor(pm, 32, 64));

            // T13 defer-max: only rescale when some row grew by >8 (log2 domain)
            if (!__all(pm - m_r <= 8.f)) {
                const float mn = fmaxf(m_r, pm);
                const float sc = exp2f(m_r - mn);
                l_r *= sc;
                #pragma unroll
                for (int ni = 0; ni < 4; ++ni) o[ni] *= sc;
                m_r = mn;
            }

            float rs = 0.f;
            #pragma unroll
            for (int ni = 0; ni < 4; ++ni)
                #pragma unroll
                for (int e = 0; e < 4; ++e) {
                    const float pv_ = exp2f(s[ni][e] - m_r);
                    s[ni][e] = pv_;
                    rs += pv_;
                }
            rs += __shfl_xor(rs, 16, 64);
            rs += __shfl_xor(rs, 32, 64);
            l_r += rs;

            // P -> LDS: lane owns (q=lr, kv=ni*16+lh*4+e); cvt_pk + 8B stores, swizzled
            #pragma unroll
            for (int ni = 0; ni < 4; ++ni) {
                const unsigned u0 = cvtpk(s[ni][0], s[ni][1]);
                const unsigned u1 = cvtpk(s[ni][2], s[ni][3]);
                *(uint2*)&Ps[w][lr * 64 + ((ni * 16 + lh * 4) ^ ((lr & 7) << 3))] = make_uint2(u0, u1);
            }
            __asm__ volatile("s_waitcnt lgkmcnt(0)" ::: "memory");
            __builtin_amdgcn_sched_barrier(0);
            const s16x8 pf0 = *(const s16x8*)&Ps[w][lr * 64 + g0];   // P^T B-frag
            const s16x8 pf1 = *(const s16x8*)&Ps[w][lr * 64 + g1];

            // O^T += V^T P^T: A=V^T-frag, B=P^T-frag
            __builtin_amdgcn_s_setprio(1);
            #pragma unroll
            for (int ni = 0; ni < 4; ++ni) {
                const int dd = ni * 16 + lr;
                s16x8 v0 = *(const s16x8*)&Vs[cur][dd * 64 + g0];
                s16x8 v1 = *(const s16x8*)&Vs[cur][dd * 64 + g1];
                o[ni] = __builtin_amdgcn_mfma_f32_16x16x32_bf16(v0, pf0, o[ni], 0, 0, 0);
                o[ni] = __builtin_amdgcn_mfma_f32_16x16x32_bf16(v1, pf1, o[ni], 0, 0, 0);
            }
            __builtin_amdgcn_s_setprio(0);
        }
        __syncthreads();
    }

    // epilogue: lane owns q-row t=q0+w*16+lr, d=ni*16+lh*4+e; cvt_pk + 8B stores
    const int t = q0 + w * 16 + lr;
    const float inv = 1.f / l_r;
    const size_t base = ((size_t)(b * T_SEQ) + t) * D_MODEL;
    #pragma unroll
    for (int ni = 0; ni < 4; ++ni) {
        const unsigned u0 = cvtpk(o[ni][0] * inv, o[ni][1] * inv);
        const unsigned u1 = cvtpk(o[ni][2] * inv, o[ni][3] * inv);
        const int c = h * HDIM + ni * 16 + lh * 4;
        *(uint2*)&Ob[base + (c ^ ((t & 7) << 3))] = make_uint2(u0, u1);
    }
}

extern "C" void kernel_launch(void* const* d_in, const int* in_sizes, int n_in,
                              void* d_out, int out_size, void* d_ws, size_t ws_size,
                              hipStream_t stream) {
    const float* x  = (const float*)d_in[0];
    const float* Wq = (const float*)d_in[1];
    const float* bq = (const float*)d_in[2];
    const float* Wk = (const float*)d_in[3];
    const float* bk = (const float*)d_in[4];
    const float* Wv = (const float*)d_in[5];
    const float* bv = (const float*)d_in[6];
    const float* Wo = (const float*)d_in[7];
    const float* bo = (const float*)d_in[8];

    ushortT* xb  = (ushortT*)d_ws;                    // swizzled bf16 copies (contiguous)
    ushortT* Wqb = xb  + (size_t)M_ROWS * D_MODEL;
    ushortT* Wkb = Wqb + (size_t)D_MODEL * D_MODEL;
    ushortT* Wvb = Wkb + (size_t)D_MODEL * D_MODEL;
    ushortT* Wob = Wvb + (size_t)D_MODEL * D_MODEL;
    ushortT* Qb  = Wob + (size_t)D_MODEL * D_MODEL;   // (BH,T,64) plain, log2-scaled
    ushortT* Kb  = Qb  + (size_t)M_ROWS * D_MODEL;    // (BH,T,64) swizzled
    ushortT* Vtb = Kb  + (size_t)M_ROWS * D_MODEL;    // (BH,64,T) swizzled
    ushortT* Ob  = Vtb + (size_t)M_ROWS * D_MODEL;    // (B,T,D)  swizzled

    cast_all<<<6144, 256, 0, stream>>>(x, Wq, Wk, Wv, Wo, xb);

    qkv_gemm<<<dim3(64, 24), 256, 0, stream>>>(xb, Wqb, Wkb, Wvb, bq, bk, bv, Qb, Kb, Vtb);

    attn_fwd<<<1024, 512, 0, stream>>>(Qb, Kb, Vtb, Ob);

    out_gemm<<<dim3(64, 8), 256, 0, stream>>>(Ob, Wob, bo, (float*)d_out);
}

// Round 10
// 290.459 us; speedup vs baseline: 1.0656x; 1.0656x over previous
//
#include <hip/hip_runtime.h>
#include <hip/hip_bf16.h>

#define D_MODEL 1024
#define T_SEQ   2048
#define BATCH   4
#define NHEADS  16
#define HDIM    64
#define M_ROWS  (BATCH * T_SEQ)   // 8192
#define QSCALE  (0.125f * 1.44269504088896340736f)   // 1/sqrt(64) * log2(e)

typedef unsigned short ushortT;
typedef __attribute__((ext_vector_type(4))) float f32x4;
typedef __attribute__((ext_vector_type(8))) short s16x8;

#define GP(p) ((const __attribute__((address_space(1))) void*)(p))
#define LP(p) ((__attribute__((address_space(3))) void*)(p))

static __device__ __forceinline__ ushortT f2b(float f) {
    union { float f; unsigned u; } v; v.f = f;
    unsigned r = v.u + 0x7fffu + ((v.u >> 16) & 1u);
    return (ushortT)(r >> 16);
}

static __device__ __forceinline__ unsigned cvtpk(float lo, float hi) {
    unsigned r;
    asm("v_cvt_pk_bf16_f32 %0, %1, %2" : "=v"(r) : "v"(lo), "v"(hi));
    return r;
}

// ---- fused cast: x + 4 weights, fp32 -> bf16, XOR-swizzled by (row&7) ----
__global__ void cast_all(const float* __restrict__ x,
                         const float* __restrict__ Wq, const float* __restrict__ Wk,
                         const float* __restrict__ Wv, const float* __restrict__ Wo,
                         ushortT* __restrict__ dst) {
    const int i = blockIdx.x * 256 + threadIdx.x;
    const float* src; int g, ob;
    if (i < 1048576)      { src = x;  g = i;           ob = 0; }
    else if (i < 1179648) { src = Wq; g = i - 1048576; ob = 1048576; }
    else if (i < 1310720) { src = Wk; g = i - 1179648; ob = 1179648; }
    else if (i < 1441792) { src = Wv; g = i - 1310720; ob = 1310720; }
    else                  { src = Wo; g = i - 1441792; ob = 1441792; }
    const float4* s = (const float4*)src;
    float4 a = s[g * 2], b = s[g * 2 + 1];
    s16x8 r;
    r[0] = f2b(a.x); r[1] = f2b(a.y); r[2] = f2b(a.z); r[3] = f2b(a.w);
    r[4] = f2b(b.x); r[5] = f2b(b.y); r[6] = f2b(b.z); r[7] = f2b(b.w);
    ((s16x8*)dst)[ob + (g ^ ((g >> 7) & 7))] = r;
}

// ============ 256x256 8-wave counted-vmcnt GEMM (T2+T3+T4+T5) =====================
// A, Bw stored granule-swizzled: elem[m][k ^ ((m&7)<<3)].  BK=64, 16 K-tiles.
// LDS 128KB (2 buf x (256x64 A + 256x64 B)), 1 block/CU, 512 thr = 8 waves (2M x 4N).
// Pipeline: 2 tiles in flight (16 loads); per-iter s_waitcnt vmcnt(8) + raw barrier;
// stage tile t+2 after the phase-3 barrier (buf free). Full drain only at t=15.

#define G256_PRE()                                                       \
    const int tid  = threadIdx.x;                                        \
    const int wave = tid >> 6, lane = tid & 63;                          \
    const int wm = wave >> 2, wn = wave & 3;                             \
    const int lr = lane & 15, lh = lane >> 4;                            \
    const int srow = tid >> 3, sg = tid & 7;                             \
    const int gA0 = (lh ^ (lr & 7)) * 8;                                 \
    const int gA1 = ((4 + lh) ^ (lr & 7)) * 8;                           \
    f32x4 acc[8][4] = {};                                                \
    const ushortT* Ag = A  + (size_t)(m0  + srow) * 1024 + sg * 8;       \
    const ushortT* Bg = Bw + (size_t)(n0s + srow) * 1024 + sg * 8;

#define STG(buf, kt)                                                                     \
    do {                                                                                 \
        const int k0_ = (kt) * 64;                                                       \
        _Pragma("unroll")                                                                \
        for (int is = 0; is < 4; ++is) {                                                 \
            __builtin_amdgcn_global_load_lds(GP(Ag + (size_t)(is * 64) * 1024 + k0_),    \
                                             LP(&As[buf][is * 4096 + tid * 8]), 16, 0, 0); \
            __builtin_amdgcn_global_load_lds(GP(Bg + (size_t)(is * 64) * 1024 + k0_),    \
                                             LP(&Bs[buf][is * 4096 + tid * 8]), 16, 0, 0); \
        }                                                                                \
    } while (0)

#define RD_A(mh)                                                         \
    { _Pragma("unroll")                                                  \
      for (int mi = 0; mi < 4; ++mi) {                                   \
          const int rb = (wm * 128 + (mh) * 64 + mi * 16 + lr) * 64;     \
          af[mi][0] = *(const s16x8*)&As[cur][rb + gA0];                 \
          af[mi][1] = *(const s16x8*)&As[cur][rb + gA1];                 \
      } }

#define RD_B(nh)                                                         \
    { _Pragma("unroll")                                                  \
      for (int ni = 0; ni < 2; ++ni) {                                   \
          const int rb = (wn * 64 + (nh) * 32 + ni * 16 + lr) * 64;      \
          bf_[ni][0] = *(const s16x8*)&Bs[cur][rb + gA0];                 \
          bf_[ni][1] = *(const s16x8*)&Bs[cur][rb + gA1];                 \
      } }

#define MM(mh, nh)                                                                       \
    { __builtin_amdgcn_s_setprio(1);                                                     \
      _Pragma("unroll")                                                                  \
      for (int mi = 0; mi < 4; ++mi)                                                     \
          _Pragma("unroll")                                                              \
          for (int ni = 0; ni < 2; ++ni) {                                               \
              acc[(mh)*4+mi][(nh)*2+ni] = __builtin_amdgcn_mfma_f32_16x16x32_bf16(       \
                  af[mi][0], bf_[ni][0], acc[(mh)*4+mi][(nh)*2+ni], 0, 0, 0);            \
              acc[(mh)*4+mi][(nh)*2+ni] = __builtin_amdgcn_mfma_f32_16x16x32_bf16(       \
                  af[mi][1], bf_[ni][1], acc[(mh)*4+mi][(nh)*2+ni], 0, 0, 0);            \
          }                                                                              \
      __builtin_amdgcn_s_setprio(0); }

#define LGKM0 do { asm volatile("s_waitcnt lgkmcnt(0)" ::: "memory"); \
                   __builtin_amdgcn_sched_barrier(0); } while (0)

#define G256_KLOOP()                                                     \
    STG(0, 0);                                                           \
    STG(1, 1);                                                           \
    _Pragma("unroll 1")                                                  \
    for (int t = 0; t < 16; ++t) {                                       \
        const int cur = t & 1;                                           \
        if (t < 15) { asm volatile("s_waitcnt vmcnt(8)" ::: "memory"); } \
        else        { asm volatile("s_waitcnt vmcnt(0)" ::: "memory"); } \
        __builtin_amdgcn_s_barrier();                                    \
        __builtin_amdgcn_sched_barrier(0);                               \
        s16x8 af[4][2], bf_[2][2];                                       \
        RD_A(0); RD_B(0); LGKM0; MM(0, 0);                               \
        RD_B(1); LGKM0; MM(0, 1);                                        \
        RD_A(1); LGKM0; MM(1, 1);                                        \
        RD_B(0); LGKM0;                                                  \
        __builtin_amdgcn_s_barrier();                                    \
        __builtin_amdgcn_sched_barrier(0);                               \
        if (t < 14) STG(cur, t + 2);                                     \
        MM(1, 0);                                                        \
    }

// ---- fused QKV GEMM: 1D grid 384 = 32 m-tiles x 12 n-tiles (3 segs x 4) ----
__global__ __launch_bounds__(512, 2) void qkv_gemm(
    const ushortT* __restrict__ A,
    const ushortT* __restrict__ Wq, const ushortT* __restrict__ Wk, const ushortT* __restrict__ Wv,
    const float* __restrict__ bq, const float* __restrict__ bk, const float* __restrict__ bv,
    ushortT* __restrict__ Qb, ushortT* __restrict__ Kb, ushortT* __restrict__ Vtb)
{
    __shared__ __attribute__((aligned(16))) ushortT As[2][256 * 64];
    __shared__ __attribute__((aligned(16))) ushortT Bs[2][256 * 64];

    // XCD-chunked swizzle: 48 blocks/XCD share 4 m-panels
    const int swz = (blockIdx.x & 7) * 48 + (blockIdx.x >> 3);
    const int m0  = (swz / 12) * 256;
    const int y   = swz % 12;
    const int seg = y >> 2;
    const int n0s = (y & 3) * 256;

    const ushortT* Bw   = (seg == 0) ? Wq : (seg == 1) ? Wk : Wv;
    const float*   bias = (seg == 0) ? bq : (seg == 1) ? bk : bv;
    const float    scale = (seg == 0) ? QSCALE : 1.0f;
    ushortT*       outp = (seg == 0) ? Qb : (seg == 1) ? Kb : Vtb;

    G256_PRE();
    G256_KLOOP();

    #pragma unroll
    for (int mi = 0; mi < 8; ++mi) {
        #pragma unroll
        for (int na = 0; na < 4; ++na) {
            const int c = n0s + wn * 64 + na * 16 + lr;
            const float bv_ = bias[c];
            #pragma unroll
            for (int e = 0; e < 4; ++e) {
                const int r = m0 + wm * 128 + mi * 16 + lh * 4 + e;
                const float val = (acc[mi][na][e] + bv_) * scale;
                const int bb = r >> 11, tt = r & 2047;
                const int h = c >> 6,  d = c & 63;
                size_t idx;
                if (seg == 2)      idx = ((size_t)(bb * NHEADS + h) * HDIM + d) * T_SEQ + (tt ^ ((d & 7) << 3));
                else if (seg == 1) idx = ((size_t)(bb * NHEADS + h) * T_SEQ + tt) * HDIM + (d ^ ((tt & 7) << 3));
                else               idx = ((size_t)(bb * NHEADS + h) * T_SEQ + tt) * HDIM + d;
                outp[idx] = f2b(val);
            }
        }
    }
}

// ---- output GEMM: 1D grid 128 = 32 m-tiles x 4 n-tiles, fp32 out ----
__global__ __launch_bounds__(512, 2) void out_gemm(
    const ushortT* __restrict__ A, const ushortT* __restrict__ Bw,
    const float* __restrict__ bias, float* __restrict__ outp)
{
    __shared__ __attribute__((aligned(16))) ushortT As[2][256 * 64];
    __shared__ __attribute__((aligned(16))) ushortT Bs[2][256 * 64];

    const int swz = (blockIdx.x & 7) * 16 + (blockIdx.x >> 3);
    const int m0  = (swz / 4) * 256;
    const int n0s = (swz % 4) * 256;

    G256_PRE();
    G256_KLOOP();

    #pragma unroll
    for (int mi = 0; mi < 8; ++mi) {
        #pragma unroll
        for (int na = 0; na < 4; ++na) {
            const int c = n0s + wn * 64 + na * 16 + lr;
            const float bv_ = bias[c];
            #pragma unroll
            for (int e = 0; e < 4; ++e) {
                const int r = m0 + wm * 128 + mi * 16 + lh * 4 + e;
                outp[(size_t)r * 1024 + c] = acc[mi][na][e] + bv_;
            }
        }
    }
}

// ---------------- flash attention, causal, swapped-operand softmax ----------------
// 8-wave blocks (512 thr), 128 q-rows/block sharing one K/V stream.
// Grid 1024 = 64 bh x 16 q-groups; LPT order + XCD head-grouping. LDS 48KB -> 3 blk/CU.
__global__ __launch_bounds__(512, 6) void attn_fwd(
    const ushortT* __restrict__ Qb, const ushortT* __restrict__ Kb,
    const ushortT* __restrict__ Vt, ushortT* __restrict__ Ob)
{
    __shared__ __attribute__((aligned(16))) ushortT Ks[2][64 * 64];
    __shared__ __attribute__((aligned(16))) ushortT Vs[2][64 * 64];
    __shared__ __attribute__((aligned(16))) ushortT Ps[8][16 * 64];

    const int tid = threadIdx.x;
    const int w = tid >> 6, lane = tid & 63;
    const int lr = lane & 15, lh = lane >> 4;

    const int blk  = blockIdx.x;
    const int bh   = (blk & 7) * 8 + ((blk >> 3) & 7);  // 8 heads per XCD
    const int grp  = blk >> 6;                          // 0..15
    const int qg64 = (15 - grp) * 2;                    // LPT: big first
    const int q0   = qg64 * 64;
    const int last = qg64 + 1;

    const int srow = tid >> 3;       // 0..63
    const int sk   = (tid & 7) * 8;

    const ushortT* Kbh = Kb + (size_t)bh * T_SEQ * HDIM;
    const ushortT* Vbh = Vt + (size_t)bh * HDIM * T_SEQ;
    const int b = bh >> 4, h = bh & 15;

    const int g0 = (lh       ^ (lr & 7)) * 8;
    const int g1 = ((4 + lh) ^ (lr & 7)) * 8;

    #define STAGE(buf, kt_) do { \
        const int k0_ = (kt_) * 64; \
        __builtin_amdgcn_global_load_lds(GP(Kbh + (size_t)(k0_ + srow) * HDIM + sk), \
                                         LP(&Ks[buf][srow * 64 + sk]), 16, 0, 0); \
        __builtin_amdgcn_global_load_lds(GP(Vbh + (size_t)srow * T_SEQ + k0_ + sk), \
                                         LP(&Vs[buf][srow * 64 + sk]), 16, 0, 0); \
    } while (0)

    STAGE(0, 0);

    const ushortT* qrow = Qb + ((size_t)bh * T_SEQ + q0 + w * 16 + lr) * HDIM;
    const s16x8 qf0 = *(const s16x8*)(qrow + lh * 8);
    const s16x8 qf1 = *(const s16x8*)(qrow + 32 + lh * 8);

    float m_r = -1e30f, l_r = 0.f;
    f32x4 o[4] = {};

    const int dt = qg64 + (w >> 2);

    __syncthreads();

    for (int kt = 0; kt <= last; ++kt) {
        const int cur = kt & 1;
        if (kt < last) STAGE(cur ^ 1, kt + 1);

        if (kt <= dt) {
            f32x4 s[4];
            __builtin_amdgcn_s_setprio(1);
            #pragma unroll
            for (int ni = 0; ni < 4; ++ni) {
                const int rr = ni * 16 + lr;
                s16x8 b0 = *(const s16x8*)&Ks[cur][rr * 64 + g0];
                s16x8 b1 = *(const s16x8*)&Ks[cur][rr * 64 + g1];
                f32x4 t = {};
                t = __builtin_amdgcn_mfma_f32_16x16x32_bf16(b0, qf0, t, 0, 0, 0);
                t = __builtin_amdgcn_mfma_f32_16x16x32_bf16(b1, qf1, t, 0, 0, 0);
                s[ni] = t;
            }
            __builtin_amdgcn_s_setprio(0);

            if (kt == dt) {
                #pragma unroll
                for (int ni = 0; ni < 4; ++ni)
                    #pragma unroll
                    for (int e = 0; e < 4; ++e)
                        if (ni * 16 + lh * 4 + e > (w & 3) * 16 + lr) s[ni][e] = -1e30f;
            }

            float pm;
            {
                float a0 = fmaxf(fmaxf(s[0][0], s[0][1]), fmaxf(s[0][2], s[0][3]));
                float a1 = fmaxf(fmaxf(s[1][0], s[1][1]), fmaxf(s[1][2], s[1][3]));
                float a2 = fmaxf(fmaxf(s[2][0], s[2][1]), fmaxf(s[2][2], s[2][3]));
                float a3 = fmaxf(fmaxf(s[3][0], s[3][1]), fmaxf(s[3][2], s[3][3]));
                pm = fmaxf(fmaxf(a0, a1), fmaxf(a2, a3));
            }
            pm = fmaxf(pm, __shfl_xor(pm, 16, 64));
            pm = fmaxf(pm, __shfl_xor(pm, 32, 64));

            if (!__all(pm - m_r <= 8.f)) {
                const float mn = fmaxf(m_r, pm);
                const float sc = exp2f(m_r - mn);
                l_r *= sc;
                #pragma unroll
                for (int ni = 0; ni < 4; ++ni) o[ni] *= sc;
                m_r = mn;
            }

            float rs = 0.f;
            #pragma unroll
            for (int ni = 0; ni < 4; ++ni)
                #pragma unroll
                for (int e = 0; e < 4; ++e) {
                    const float pv_ = exp2f(s[ni][e] - m_r);
                    s[ni][e] = pv_;
                    rs += pv_;
                }
            rs += __shfl_xor(rs, 16, 64);
            rs += __shfl_xor(rs, 32, 64);
            l_r += rs;

            #pragma unroll
            for (int ni = 0; ni < 4; ++ni) {
                const unsigned u0 = cvtpk(s[ni][0], s[ni][1]);
                const unsigned u1 = cvtpk(s[ni][2], s[ni][3]);
                *(uint2*)&Ps[w][lr * 64 + ((ni * 16 + lh * 4) ^ ((lr & 7) << 3))] = make_uint2(u0, u1);
            }
            __asm__ volatile("s_waitcnt lgkmcnt(0)" ::: "memory");
            __builtin_amdgcn_sched_barrier(0);
            const s16x8 pf0 = *(const s16x8*)&Ps[w][lr * 64 + g0];
            const s16x8 pf1 = *(const s16x8*)&Ps[w][lr * 64 + g1];

            __builtin_amdgcn_s_setprio(1);
            #pragma unroll
            for (int ni = 0; ni < 4; ++ni) {
                const int dd = ni * 16 + lr;
                s16x8 v0 = *(const s16x8*)&Vs[cur][dd * 64 + g0];
                s16x8 v1 = *(const s16x8*)&Vs[cur][dd * 64 + g1];
                o[ni] = __builtin_amdgcn_mfma_f32_16x16x32_bf16(v0, pf0, o[ni], 0, 0, 0);
                o[ni] = __builtin_amdgcn_mfma_f32_16x16x32_bf16(v1, pf1, o[ni], 0, 0, 0);
            }
            __builtin_amdgcn_s_setprio(0);
        }
        __syncthreads();
    }

    const int t = q0 + w * 16 + lr;
    const float inv = 1.f / l_r;
    const size_t base = ((size_t)(b * T_SEQ) + t) * D_MODEL;
    #pragma unroll
    for (int ni = 0; ni < 4; ++ni) {
        const unsigned u0 = cvtpk(o[ni][0] * inv, o[ni][1] * inv);
        const unsigned u1 = cvtpk(o[ni][2] * inv, o[ni][3] * inv);
        const int c = h * HDIM + ni * 16 + lh * 4;
        *(uint2*)&Ob[base + (c ^ ((t & 7) << 3))] = make_uint2(u0, u1);
    }
}

extern "C" void kernel_launch(void* const* d_in, const int* in_sizes, int n_in,
                              void* d_out, int out_size, void* d_ws, size_t ws_size,
                              hipStream_t stream) {
    const float* x  = (const float*)d_in[0];
    const float* Wq = (const float*)d_in[1];
    const float* bq = (const float*)d_in[2];
    const float* Wk = (const float*)d_in[3];
    const float* bk = (const float*)d_in[4];
    const float* Wv = (const float*)d_in[5];
    const float* bv = (const float*)d_in[6];
    const float* Wo = (const float*)d_in[7];
    const float* bo = (const float*)d_in[8];

    ushortT* xb  = (ushortT*)d_ws;                    // swizzled bf16 copies (contiguous)
    ushortT* Wqb = xb  + (size_t)M_ROWS * D_MODEL;
    ushortT* Wkb = Wqb + (size_t)D_MODEL * D_MODEL;
    ushortT* Wvb = Wkb + (size_t)D_MODEL * D_MODEL;
    ushortT* Wob = Wvb + (size_t)D_MODEL * D_MODEL;
    ushortT* Qb  = Wob + (size_t)D_MODEL * D_MODEL;   // (BH,T,64) plain, log2-scaled
    ushortT* Kb  = Qb  + (size_t)M_ROWS * D_MODEL;    // (BH,T,64) swizzled
    ushortT* Vtb = Kb  + (size_t)M_ROWS * D_MODEL;    // (BH,64,T) swizzled
    ushortT* Ob  = Vtb + (size_t)M_ROWS * D_MODEL;    // (B,T,D)  swizzled

    cast_all<<<6144, 256, 0, stream>>>(x, Wq, Wk, Wv, Wo, xb);

    qkv_gemm<<<384, 512, 0, stream>>>(xb, Wqb, Wkb, Wvb, bq, bk, bv, Qb, Kb, Vtb);

    attn_fwd<<<1024, 512, 0, stream>>>(Qb, Kb, Vtb, Ob);

    out_gemm<<<128, 512, 0, stream>>>(Ob, Wob, bo, (float*)d_out);
}